// Round 15
// baseline (75.587 us; speedup 1.0000x reference)
//
#include <hip/hip_runtime.h>
#include <hip/hip_bf16.h>

#define TT 2
#define HH 48
#define WW 48
#define CC 256
#define NHEADS 8
#define HDIM 32
#define SEQ 2048
#define NPIX (TT*HH*WW)   /* 4608 */
#define NPC  (NPIX*CC)    /* 1179648 */
#define LSZ  (4*NHEADS*SEQ) /* 65536 floats per split-lsum */
#define OFS  (4*SEQ*CC)     /* shorts per split of pixel-major O = 2,097,152 */
#define SPLITS 4

typedef __attribute__((ext_vector_type(8))) short bf16x8;
typedef __attribute__((ext_vector_type(4))) short bf16x4;
typedef __attribute__((ext_vector_type(4))) float f32x4;

#if __has_builtin(__builtin_amdgcn_exp2f)
#define EXP2(x) __builtin_amdgcn_exp2f(x)
#else
#define EXP2(x) exp2f(x)
#endif
#if __has_builtin(__builtin_amdgcn_rcpf)
#define RCP(x) __builtin_amdgcn_rcpf(x)
#else
#define RCP(x) (1.0f/(x))
#endif

__device__ inline unsigned cvt_pk_bf16(float lo, float hi) {
    unsigned r;
    asm("v_cvt_pk_bf16_f32 %0, %1, %2" : "=v"(r) : "v"(lo), "v"(hi));
    return r;
}
__device__ inline f32x4 mfma16(bf16x4 a, bf16x4 b, f32x4 c) {
    asm("v_mfma_f32_16x16x16_bf16 %0, %1, %2, %0" : "+v"(c) : "v"(a), "v"(b));
    return c;
}
__device__ inline f32x4 b2f4(bf16x4 v) {
    union { bf16x4 b; unsigned short u[4]; } t; t.b = v;
    f32x4 r;
    #pragma unroll
    for (int i = 0; i < 4; ++i) { union { unsigned u; float f; } c; c.u = ((unsigned)t.u[i]) << 16; r[i] = c.f; }
    return r;
}

// ---------------- Kernel 0: fused LN + in-block W-conv + QKV (MFMA) ----------
// grid = 3 mats x 72 px-blocks x 4 oc-groups = 864; block 256 (4 waves).
// Self-contained: LN's its own 64 px into LDS; converts its own 64-row W slice
// fp32->bf16 frags into LDS. No k_pre, no global wfp/xnb.
__global__ __launch_bounds__(256) void k_qkvln(
    const float* __restrict__ x,
    const float* __restrict__ lnw, const float* __restrict__ lnb,
    const float* __restrict__ Wq, const float* __restrict__ Wk,
    const float* __restrict__ Wv,
    __hip_bfloat16* __restrict__ qb, __hip_bfloat16* __restrict__ kb,
    __hip_bfloat16* __restrict__ vtb)
{
    __shared__ __hip_bfloat16 xn[64][264];
    __shared__ __hip_bfloat16 wlds[16384];   // 4 oct x 8 k x 512 frags
    const int tid  = threadIdx.x;
    const int wv_  = tid >> 6;
    const int lane = tid & 63;
    const int mat  = blockIdx.x / 288;
    const int r    = blockIdx.x % 288;
    const int p0   = (r >> 2) * 64;
    const int ocg  = r & 3;

    // ---- Phase A: LN of this block's 64 px (16 per wave) -> xn LDS ----
    {
        const float4 w4 = *reinterpret_cast<const float4*>(lnw + lane * 4);
        const float4 b4 = *reinterpret_cast<const float4*>(lnb + lane * 4);
        for (int i = 0; i < 16; ++i) {
            const int pl = wv_ * 16 + i;
            const float4 xv = *reinterpret_cast<const float4*>(
                x + (size_t)(p0 + pl) * CC + lane * 4);
            float s  = xv.x + xv.y + xv.z + xv.w;
            float s2 = xv.x*xv.x + xv.y*xv.y + xv.z*xv.z + xv.w*xv.w;
            #pragma unroll
            for (int m = 1; m < 64; m <<= 1) {
                s  += __shfl_xor(s,  m, 64);
                s2 += __shfl_xor(s2, m, 64);
            }
            const float mu   = s * (1.0f / CC);
            const float var  = s2 * (1.0f / CC) - mu * mu;
            const float rstd = rsqrtf(var + 1e-6f);
            uint2 st;
            st.x = cvt_pk_bf16((xv.x - mu) * rstd * w4.x + b4.x,
                               (xv.y - mu) * rstd * w4.y + b4.y);
            st.y = cvt_pk_bf16((xv.z - mu) * rstd * w4.z + b4.z,
                               (xv.w - mu) * rstd * w4.w + b4.w);
            *reinterpret_cast<uint2*>(&xn[pl][lane * 4]) = st;
        }
    }
    // ---- Phase A2: convert this block's 64x256 W slice -> frag order LDS ----
    {
        const float* Wmat = (mat == 0) ? Wq : ((mat == 1) ? Wk : Wv);
        const float sc = (mat == 0)
            ? (0.17677669529663688f * 1.4426950408889634f) : 1.0f;
        #pragma unroll
        for (int i = 0; i < 16; ++i) {
            const int ch   = i * 256 + tid;        // 4096 float4 chunks
            const int rloc = ch >> 6;              // local row 0..63
            const int col  = (ch & 63) * 4;
            const float4 t = *reinterpret_cast<const float4*>(
                Wmat + (size_t)(ocg * 64 + rloc) * 256 + col);
            uint2 st;
            st.x = cvt_pk_bf16(t.x * sc, t.y * sc);
            st.y = cvt_pk_bf16(t.z * sc, t.w * sc);
            const int octl = rloc >> 4, m16r = rloc & 15;
            const int k = col >> 5, g2 = (col >> 3) & 3, j0 = col & 7;
            const int off = ((octl * 8 + k) * 64 + g2 * 16 + m16r) * 8 + j0;
            *reinterpret_cast<uint2*>(&wlds[off]) = st;
        }
    }
    __syncthreads();

    // ---- Phase B: MFMA projection ----
    const int m16 = lane & 15, g = lane >> 4;
    bf16x8 xf[8];
    #pragma unroll
    for (int k = 0; k < 8; ++k)
        xf[k] = *reinterpret_cast<const bf16x8*>(&xn[wv_ * 16 + m16][k * 32 + g * 8]);

    const int pxb = p0 + wv_ * 16;
    #pragma unroll
    for (int o4 = 0; o4 < 4; ++o4) {
        const int octG = ocg * 4 + o4;
        const __hip_bfloat16* wt = &wlds[(o4 * 8) * 512];
        f32x4 c = {0.f, 0.f, 0.f, 0.f};
        if (mat < 2) {
            #pragma unroll
            for (int k = 0; k < 8; ++k) {
                const bf16x8 wf = *reinterpret_cast<const bf16x8*>(wt + (size_t)k * 512 + lane * 8);
                c = __builtin_amdgcn_mfma_f32_16x16x32_bf16(wf, xf[k], c, 0, 0, 0);
            }
            uint2 st;
            st.x = cvt_pk_bf16(c[0], c[1]);
            st.y = cvt_pk_bf16(c[2], c[3]);
            __hip_bfloat16* dst = (mat == 0) ? qb : kb;
            *reinterpret_cast<uint2*>(dst + (size_t)(pxb + m16) * CC + octG * 16 + g * 4) = st;
        } else {
            #pragma unroll
            for (int k = 0; k < 8; ++k) {
                const bf16x8 wf = *reinterpret_cast<const bf16x8*>(wt + (size_t)k * 512 + lane * 8);
                c = __builtin_amdgcn_mfma_f32_16x16x32_bf16(xf[k], wf, c, 0, 0, 0);
            }
            uint2 st;
            st.x = cvt_pk_bf16(c[0], c[1]);
            st.y = cvt_pk_bf16(c[2], c[3]);
            *reinterpret_cast<uint2*>(vtb + (size_t)(octG * 16 + m16) * NPIX + pxb + g * 4) = st;
        }
    }
}

// ---------------- Kernel 1: MFMA flash attention, LDS-resident K/V -----------
// 512-thr blocks (8 waves); grid 512 = 128 grps x 4 q-chunks. (r13 verbatim)
__global__ __launch_bounds__(512, 4) void k_attn(
    const __hip_bfloat16* __restrict__ qb, const __hip_bfloat16* __restrict__ kb,
    const __hip_bfloat16* __restrict__ vtb, __hip_bfloat16* __restrict__ Opm,
    float* __restrict__ lsb)
{
    __shared__ __hip_bfloat16 lds[32768];   // K: [0,16384) V: [16384,32768)
    const int tid  = threadIdx.x;
    const int lane = tid & 63;
    const int wsub = tid >> 6;
    const int bid  = blockIdx.x;
    const int grp  = bid & 127;         // -> fixed XCD (bid%8 == grp%8)
    const int qq   = bid >> 7;          // 0..3
    const int split = grp >> 5;         // 0..3
    const int wh    = grp & 31;
    const int win   = wh >> 3;
    const int head  = wh & 7;
    const int rs = (win >> 1) * 16, cs = (win & 1) * 16;
    const int tt = split >> 1;
    const int y0 = (split & 1) * 16;
    const int rowbase = (tt * HH + rs) * WW + cs;
    const int qblk64 = qq * 8 + wsub;
    const int g = lane >> 4, q16 = lane & 15;

    // K fill: 32 tiles x 64 lanes x 16B; LDS linear, 64B/px lines
    {
        const int k16 = tid & 15, gk = (tid >> 4) & 3;
        #pragma unroll
        for (int pass = 0; pass < 4; ++pass) {
            const int slot = pass * 512 + tid;
            const int T = slot >> 6;
            const int key = T * 16 + k16;
            const int pix = rowbase + (y0 + (key >> 5)) * WW + (key & 31);
            *reinterpret_cast<bf16x8*>(&lds[(size_t)slot * 8]) =
                *reinterpret_cast<const bf16x8*>(kb + (size_t)pix * CC + head * HDIM + gk * 8);
        }
        // V fill: coalesced 16B of 8 consecutive keys, scatter 2x8B
        const int cch = tid >> 4, s16 = tid & 15;
        const int dtc = cch >> 4, qvc = cch & 15;
        const __hip_bfloat16* vrow = vtb + (size_t)(head * HDIM + cch) * NPIX;
        #pragma unroll
        for (int i = 0; i < 4; ++i) {
            const int key0 = i * 128 + s16 * 8;
            const int pix0 = rowbase + (y0 + (key0 >> 5)) * WW + (key0 & 31);
            union { bf16x8 v; bf16x4 h[2]; } u;
            u.v = *reinterpret_cast<const bf16x8*>(vrow + pix0);
            const int T2  = key0 >> 4;
            const int gv0 = (key0 & 15) >> 2;
            #pragma unroll
            for (int h = 0; h < 2; ++h) {
                const int slot = ((T2 * 2 + dtc) * 4 + gv0 + h) * 16 + qvc;
                *reinterpret_cast<bf16x4*>(&lds[16384 + (size_t)slot * 4]) = u.h[h];
            }
        }
    }

    // Q frags
    bf16x8 qf[4];
    #pragma unroll
    for (int qt = 0; qt < 4; ++qt) {
        const int s = qblk64 * 64 + qt * 16 + q16;
        const int pix = ((s >> 10) * HH + rs + ((s >> 5) & 31)) * WW + cs + (s & 31);
        qf[qt] = *reinterpret_cast<const bf16x8*>(qb + (size_t)pix * CC + head * HDIM + g * 8);
    }

    f32x4 acc[2][4];
    f32x4 accl[4];
    #pragma unroll
    for (int b = 0; b < 4; ++b) {
        acc[0][b] = (f32x4){0.f, 0.f, 0.f, 0.f};
        acc[1][b] = (f32x4){0.f, 0.f, 0.f, 0.f};
        accl[b]   = (f32x4){0.f, 0.f, 0.f, 0.f};
    }
    const short one_bf = (short)0x3F80;   // bf16 1.0
    const bf16x4 vones = {one_bf, one_bf, one_bf, one_bf};

    __syncthreads();

    const bf16x8* kvec = reinterpret_cast<const bf16x8*>(&lds[0]);
    const bf16x4* vvec = reinterpret_cast<const bf16x4*>(&lds[16384]);

    for (int it = 0; it < 16; ++it) {
        const bf16x8 kf0 = kvec[it * 128 + lane];
        const bf16x8 kf1 = kvec[it * 128 + 64 + lane];
        const bf16x4 vf00 = vvec[it * 256 + lane];
        const bf16x4 vf10 = vvec[it * 256 + 64 + lane];
        const bf16x4 vf01 = vvec[it * 256 + 128 + lane];
        const bf16x4 vf11 = vvec[it * 256 + 192 + lane];
        #pragma unroll
        for (int qt = 0; qt < 4; ++qt) {
            const f32x4 z = {0.f, 0.f, 0.f, 0.f};
            const f32x4 s0 = __builtin_amdgcn_mfma_f32_16x16x32_bf16(kf0, qf[qt], z, 0, 0, 0);
            const f32x4 s1 = __builtin_amdgcn_mfma_f32_16x16x32_bf16(kf1, qf[qt], z, 0, 0, 0);
            const float p00 = EXP2(s0[0]), p01 = EXP2(s0[1]);
            const float p02 = EXP2(s0[2]), p03 = EXP2(s0[3]);
            const float p10 = EXP2(s1[0]), p11 = EXP2(s1[1]);
            const float p12 = EXP2(s1[2]), p13 = EXP2(s1[3]);
            union { unsigned u[2]; bf16x4 v; } pA, pB;
            pA.u[0] = cvt_pk_bf16(p00, p01); pA.u[1] = cvt_pk_bf16(p02, p03);
            pB.u[0] = cvt_pk_bf16(p10, p11); pB.u[1] = cvt_pk_bf16(p12, p13);
            acc[0][qt] = mfma16(vf00, pA.v, acc[0][qt]);
            acc[1][qt] = mfma16(vf10, pA.v, acc[1][qt]);
            accl[qt]   = mfma16(vones, pA.v, accl[qt]);
            acc[0][qt] = mfma16(vf01, pB.v, acc[0][qt]);
            acc[1][qt] = mfma16(vf11, pB.v, acc[1][qt]);
            accl[qt]   = mfma16(vones, pB.v, accl[qt]);
        }
    }

    float* lp = lsb + (size_t)split * LSZ + (size_t)wh * SEQ;
    __hip_bfloat16* Osp = Opm + (size_t)split * OFS + (size_t)win * SEQ * CC + head * HDIM;
    #pragma unroll
    for (int qt = 0; qt < 4; ++qt) {
        const float l = accl[qt][0];
        const int s = qblk64 * 64 + qt * 16 + q16;
        if (g == 0) lp[s] = l;
        #pragma unroll
        for (int dt = 0; dt < 2; ++dt) {
            uint2 st;
            st.x = cvt_pk_bf16(acc[dt][qt][0], acc[dt][qt][1]);
            st.y = cvt_pk_bf16(acc[dt][qt][2], acc[dt][qt][3]);
            *reinterpret_cast<uint2*>(Osp + (size_t)s * CC + dt * 16 + g * 4) = st;
        }
    }
}

// ---------------- Kernel 2: split-merge + overlap-add + projection -----------
// grid 288; block 256 (4 waves); 16 px/block. Wo frags converted on the fly
// from fp32 (same cvt_pk rounding as the old prep path -> bit-identical).
__global__ __launch_bounds__(256) void k_mproj(
    const __hip_bfloat16* __restrict__ Opm, const float* __restrict__ lsb,
    const float* __restrict__ Wo, const float* __restrict__ bo,
    float* __restrict__ out)
{
    __shared__ __hip_bfloat16 md[16][264];
    const int tid  = threadIdx.x;
    const int wv_  = tid >> 6;
    const int L    = tid & 63;
    const int head = L >> 3;
    const int p0   = blockIdx.x * 16;

    for (int i = 0; i < 4; ++i) {
        const int pl = wv_ * 4 + i;
        const int p  = p0 + pl;
        const int tt  = p / (HH * WW);
        const int rem = p % (HH * WW);
        const int y   = rem / WW;
        const int xc  = rem % WW;
        f32x4 a = {0.f, 0.f, 0.f, 0.f};
        int cnt = 0;
        for (int wr = 0; wr < 2; ++wr) {
            const int ii = y - wr * 16;
            if (ii < 0 || ii >= 32) continue;
            for (int wc = 0; wc < 2; ++wc) {
                const int jj = xc - wc * 16;
                if (jj < 0 || jj >= 32) continue;
                const int win = wr * 2 + wc;
                const int srow = tt * 1024 + ii * 32 + jj;
                const size_t ob = ((size_t)win * SEQ + srow) * CC + L * 4;
                const size_t li = (size_t)(win * NHEADS + head) * SEQ + srow;
                f32x4 acc4 = {0.f, 0.f, 0.f, 0.f};
                float l = 0.f;
                #pragma unroll
                for (int sp = 0; sp < SPLITS; ++sp) {
                    acc4 += b2f4(*reinterpret_cast<const bf16x4*>(Opm + (size_t)sp * OFS + ob));
                    l += lsb[(size_t)sp * LSZ + li];
                }
                a += acc4 * RCP(l);
                ++cnt;
            }
        }
        const float ic = (cnt == 1) ? 1.0f : ((cnt == 2) ? 0.5f : 0.25f);
        uint2 st;
        st.x = cvt_pk_bf16(a[0] * ic, a[1] * ic);
        st.y = cvt_pk_bf16(a[2] * ic, a[3] * ic);
        *reinterpret_cast<uint2*>(&md[pl][L * 4]) = st;
    }
    __syncthreads();

    const int m16 = L & 15, g = L >> 4;
    bf16x8 xf[8];
    #pragma unroll
    for (int k = 0; k < 8; ++k)
        xf[k] = *reinterpret_cast<const bf16x8*>(&md[m16][k * 32 + g * 8]);

    #pragma unroll
    for (int oct = 0; oct < 4; ++oct) {
        const int octG = wv_ * 4 + oct;
        const int ocb  = octG * 16;
        const float* wor = Wo + (size_t)(octG * 16 + m16) * 256;
        f32x4 c = {0.f, 0.f, 0.f, 0.f};
        #pragma unroll
        for (int k = 0; k < 8; ++k) {
            const float4 f0 = *reinterpret_cast<const float4*>(wor + k * 32 + g * 8);
            const float4 f1 = *reinterpret_cast<const float4*>(wor + k * 32 + g * 8 + 4);
            union { unsigned u[4]; bf16x8 v; } wfu;
            wfu.u[0] = cvt_pk_bf16(f0.x, f0.y);
            wfu.u[1] = cvt_pk_bf16(f0.z, f0.w);
            wfu.u[2] = cvt_pk_bf16(f1.x, f1.y);
            wfu.u[3] = cvt_pk_bf16(f1.z, f1.w);
            c = __builtin_amdgcn_mfma_f32_16x16x32_bf16(wfu.v, xf[k], c, 0, 0, 0);
        }
        const float4 b4 = *reinterpret_cast<const float4*>(bo + ocb + g * 4);
        c[0] += b4.x; c[1] += b4.y; c[2] += b4.z; c[3] += b4.w;
        *reinterpret_cast<f32x4*>(out + (size_t)(p0 + m16) * CC + ocb + g * 4) = c;
    }
}

extern "C" void kernel_launch(void* const* d_in, const int* in_sizes, int n_in,
                              void* d_out, int out_size, void* d_ws, size_t ws_size,
                              hipStream_t stream)
{
    const float* x   = (const float*)d_in[0];
    const float* lnw = (const float*)d_in[1];
    const float* lnb = (const float*)d_in[2];
    const float* Wq  = (const float*)d_in[3];
    const float* Wk  = (const float*)d_in[4];
    const float* Wv  = (const float*)d_in[5];
    const float* Wo  = (const float*)d_in[6];
    const float* bo  = (const float*)d_in[7];

    __hip_bfloat16* qb   = (__hip_bfloat16*)d_ws;
    __hip_bfloat16* kb   = qb + NPC;
    __hip_bfloat16* vtb  = kb + NPC;
    __hip_bfloat16* Opm  = vtb + NPC;              // SPLITS*OFS shorts
    float* lsb = (float*)(Opm + (size_t)SPLITS * OFS);  // SPLITS*LSZ floats

    k_qkvln<<<864, 256, 0, stream>>>(x, lnw, lnb, Wq, Wk, Wv, qb, kb, vtb);
    k_attn<<<512, 512, 0, stream>>>(qb, kb, vtb, Opm, lsb);
    k_mproj<<<288, 256, 0, stream>>>(Opm, lsb, Wo, bo, (float*)d_out);
}

// Round 16
// 59.454 us; speedup vs baseline: 1.2714x; 1.2714x over previous
//
#include <hip/hip_runtime.h>
#include <hip/hip_bf16.h>

#define TT 2
#define HH 48
#define WW 48
#define CC 256
#define NHEADS 8
#define HDIM 32
#define SEQ 2048
#define NPIX (TT*HH*WW)   /* 4608 */
#define NPC  (NPIX*CC)    /* 1179648 */
#define LSZ  (4*NHEADS*SEQ) /* 65536 floats per split-lsum */
#define OFS  (4*SEQ*CC)     /* shorts per split of pixel-major O = 2,097,152 */
#define SPLITS 4

typedef __attribute__((ext_vector_type(8))) short bf16x8;
typedef __attribute__((ext_vector_type(4))) short bf16x4;
typedef __attribute__((ext_vector_type(4))) float f32x4;

#if __has_builtin(__builtin_amdgcn_exp2f)
#define EXP2(x) __builtin_amdgcn_exp2f(x)
#else
#define EXP2(x) exp2f(x)
#endif
#if __has_builtin(__builtin_amdgcn_rcpf)
#define RCP(x) __builtin_amdgcn_rcpf(x)
#else
#define RCP(x) (1.0f/(x))
#endif

__device__ inline unsigned cvt_pk_bf16(float lo, float hi) {
    unsigned r;
    asm("v_cvt_pk_bf16_f32 %0, %1, %2" : "=v"(r) : "v"(lo), "v"(hi));
    return r;
}
__device__ inline f32x4 b2f4(bf16x4 v) {
    union { bf16x4 b; unsigned short u[4]; } t; t.b = v;
    f32x4 r;
    #pragma unroll
    for (int i = 0; i < 4; ++i) { union { unsigned u; float f; } c; c.u = ((unsigned)t.u[i]) << 16; r[i] = c.f; }
    return r;
}

// ---------------- Kernel 0: fused weight-prep + LayerNorm --------------------
// Blocks [0,256): weights -> bf16 frag-ordered. Blocks [256,1408): LN (1x).
__global__ __launch_bounds__(256) void k_pre(
    const float* __restrict__ Wq, const float* __restrict__ Wk,
    const float* __restrict__ Wv, const float* __restrict__ Wo,
    const float* __restrict__ x,
    const float* __restrict__ lnw, const float* __restrict__ lnb,
    __hip_bfloat16* __restrict__ wfp, __hip_bfloat16* __restrict__ wofp,
    __hip_bfloat16* __restrict__ xnb)
{
    const int tid = threadIdx.x;
    if (blockIdx.x < 256) {
        const float QSC = 0.17677669529663688f * 1.4426950408889634f;
        const int idx = blockIdx.x * 256 + tid;   // 65536 float4 chunks
        const int e = idx * 4;
        const int grow = e >> 8;
        const int c = e & 255;
        const float* src;
        float sc = 1.f;
        if (grow < 256)      { src = Wq + e;          sc = QSC; }
        else if (grow < 512) { src = Wk + (e - 65536); }
        else if (grow < 768) { src = Wv + (e - 131072); }
        else                 { src = Wo + (e - 196608); }
        const float4 t = *reinterpret_cast<const float4*>(src);
        uint2 st;
        st.x = cvt_pk_bf16(t.x * sc, t.y * sc);
        st.y = cvt_pk_bf16(t.z * sc, t.w * sc);
        const int r8  = grow & 255;
        const int oct = r8 >> 4, m16 = r8 & 15;
        const int k   = c >> 5, g = (c >> 3) & 3, j0 = c & 7;
        if (grow < 768) {
            const int mat = grow >> 8;
            const size_t o = ((size_t)((mat * 16 + oct) * 8 + k) * 64 + g * 16 + m16) * 8 + j0;
            *reinterpret_cast<uint2*>(wfp + o) = st;
        } else {
            const size_t o = ((size_t)(oct * 8 + k) * 64 + g * 16 + m16) * 8 + j0;
            *reinterpret_cast<uint2*>(wofp + o) = st;
        }
    } else {
        const int lane = tid & 63;
        const int pix  = (blockIdx.x - 256) * 4 + (tid >> 6);
        const float4 xv = *reinterpret_cast<const float4*>(x + (size_t)pix * CC + lane * 4);
        float s  = xv.x + xv.y + xv.z + xv.w;
        float s2 = xv.x*xv.x + xv.y*xv.y + xv.z*xv.z + xv.w*xv.w;
        #pragma unroll
        for (int m = 1; m < 64; m <<= 1) {
            s  += __shfl_xor(s,  m, 64);
            s2 += __shfl_xor(s2, m, 64);
        }
        const float mu   = s * (1.0f / CC);
        const float var  = s2 * (1.0f / CC) - mu * mu;
        const float rstd = rsqrtf(var + 1e-6f);
        const float4 w4 = *reinterpret_cast<const float4*>(lnw + lane * 4);
        const float4 b4 = *reinterpret_cast<const float4*>(lnb + lane * 4);
        uint2 st;
        st.x = cvt_pk_bf16((xv.x - mu) * rstd * w4.x + b4.x, (xv.y - mu) * rstd * w4.y + b4.y);
        st.y = cvt_pk_bf16((xv.z - mu) * rstd * w4.z + b4.z, (xv.w - mu) * rstd * w4.w + b4.w);
        *reinterpret_cast<uint2*>(xnb + (size_t)pix * CC + lane * 4) = st;
    }
}

// ---------------- Kernel 1: QKV projection (MFMA, 2x W reuse) ----------------
// grid = 3 mats x 36 px-blocks x 4 oc-groups = 432; block 256 (4 waves).
__global__ __launch_bounds__(256) void k_qkv(
    const __hip_bfloat16* __restrict__ xnb,
    const __hip_bfloat16* __restrict__ wfp,
    __hip_bfloat16* __restrict__ qb, __hip_bfloat16* __restrict__ kb,
    __hip_bfloat16* __restrict__ vtb)
{
    const int tid  = threadIdx.x;
    const int wv_  = tid >> 6;
    const int lane = tid & 63;
    const int mat  = blockIdx.x / 144;
    const int r    = blockIdx.x % 144;
    const int p0   = (r >> 2) * 128;
    const int ocg  = r & 3;
    const int m16 = lane & 15, g = lane >> 4;
    const int pxb = p0 + wv_ * 16;      // tile0; tile1 = pxb + 64

    bf16x8 xf0[8], xf1[8];
    #pragma unroll
    for (int k = 0; k < 8; ++k) {
        xf0[k] = *reinterpret_cast<const bf16x8*>(
            xnb + (size_t)(pxb + m16) * CC + k * 32 + g * 8);
        xf1[k] = *reinterpret_cast<const bf16x8*>(
            xnb + (size_t)(pxb + 64 + m16) * CC + k * 32 + g * 8);
    }

    #pragma unroll
    for (int o4 = 0; o4 < 4; ++o4) {
        const int oct = ocg * 4 + o4;
        const __hip_bfloat16* wt = wfp + ((size_t)(mat * 16 + oct) * 8) * 512;
        f32x4 c0 = {0.f, 0.f, 0.f, 0.f};
        f32x4 c1 = {0.f, 0.f, 0.f, 0.f};
        if (mat < 2) {
            #pragma unroll
            for (int k = 0; k < 8; ++k) {
                const bf16x8 wf = *reinterpret_cast<const bf16x8*>(wt + (size_t)k * 512 + lane * 8);
                c0 = __builtin_amdgcn_mfma_f32_16x16x32_bf16(wf, xf0[k], c0, 0, 0, 0);
                c1 = __builtin_amdgcn_mfma_f32_16x16x32_bf16(wf, xf1[k], c1, 0, 0, 0);
            }
            __hip_bfloat16* dst = (mat == 0) ? qb : kb;
            uint2 st0, st1;
            st0.x = cvt_pk_bf16(c0[0], c0[1]);
            st0.y = cvt_pk_bf16(c0[2], c0[3]);
            st1.x = cvt_pk_bf16(c1[0], c1[1]);
            st1.y = cvt_pk_bf16(c1[2], c1[3]);
            *reinterpret_cast<uint2*>(dst + (size_t)(pxb + m16) * CC + oct * 16 + g * 4) = st0;
            *reinterpret_cast<uint2*>(dst + (size_t)(pxb + 64 + m16) * CC + oct * 16 + g * 4) = st1;
        } else {
            #pragma unroll
            for (int k = 0; k < 8; ++k) {
                const bf16x8 wf = *reinterpret_cast<const bf16x8*>(wt + (size_t)k * 512 + lane * 8);
                c0 = __builtin_amdgcn_mfma_f32_16x16x32_bf16(xf0[k], wf, c0, 0, 0, 0);
                c1 = __builtin_amdgcn_mfma_f32_16x16x32_bf16(xf1[k], wf, c1, 0, 0, 0);
            }
            uint2 st0, st1;
            st0.x = cvt_pk_bf16(c0[0], c0[1]);
            st0.y = cvt_pk_bf16(c0[2], c0[3]);
            st1.x = cvt_pk_bf16(c1[0], c1[1]);
            st1.y = cvt_pk_bf16(c1[2], c1[3]);
            *reinterpret_cast<uint2*>(vtb + (size_t)(oct * 16 + m16) * NPIX + pxb + g * 4) = st0;
            *reinterpret_cast<uint2*>(vtb + (size_t)(oct * 16 + m16) * NPIX + pxb + 64 + g * 4) = st1;
        }
    }
}

// ---------------- Kernel 2: MFMA flash attention, LDS-resident K/V -----------
// 512-thr blocks (8 waves); grid 512 = 128 grps x 4 q-chunks.
// K=32 PV consolidation: V LDS stores per-lane 8-key frags in the permuted
// order pi(g,j) = (j<4 ? 4g+j : 16+4g+j-4) matching P's packed {pA,pB} B-frag,
// so PV = 2 MFMA(16x16x32) and lsum = 1 MFMA(ones) per (it,qt).
__global__ __launch_bounds__(512, 4) void k_attn(
    const __hip_bfloat16* __restrict__ qb, const __hip_bfloat16* __restrict__ kb,
    const __hip_bfloat16* __restrict__ vtb, __hip_bfloat16* __restrict__ Opm,
    float* __restrict__ lsb)
{
    __shared__ __hip_bfloat16 lds[32768];   // K: [0,16384) V: [16384,32768)
    const int tid  = threadIdx.x;
    const int lane = tid & 63;
    const int wsub = tid >> 6;
    const int bid  = blockIdx.x;
    const int grp  = bid & 127;         // -> fixed XCD (bid%8 == grp%8)
    const int qq   = bid >> 7;          // 0..3
    const int split = grp >> 5;         // 0..3
    const int wh    = grp & 31;
    const int win   = wh >> 3;
    const int head  = wh & 7;
    const int rs = (win >> 1) * 16, cs = (win & 1) * 16;
    const int tt = split >> 1;
    const int y0 = (split & 1) * 16;
    const int rowbase = (tt * HH + rs) * WW + cs;
    const int qblk64 = qq * 8 + wsub;
    const int g = lane >> 4, q16 = lane & 15;

    // ---- K fill: 32 tiles x 64 lanes x 16B; LDS linear, 64B/px lines ----
    {
        const int k16 = tid & 15, gk = (tid >> 4) & 3;
        #pragma unroll
        for (int pass = 0; pass < 4; ++pass) {
            const int slot = pass * 512 + tid;
            const int T = slot >> 6;
            const int key = T * 16 + k16;
            const int pix = rowbase + (y0 + (key >> 5)) * WW + (key & 31);
            *reinterpret_cast<bf16x8*>(&lds[(size_t)slot * 8]) =
                *reinterpret_cast<const bf16x8*>(kb + (size_t)pix * CC + head * HDIM + gk * 8);
        }
        // ---- V fill: coalesced 16B of 8 consecutive keys; scatter 2x8B to
        // the permuted-frag layout slot = it*128 + dt*64 + g*16 + q, byte h*8.
        const int cch = tid >> 4, s16 = tid & 15;
        const int dtc = cch >> 4, qvc = cch & 15;
        const __hip_bfloat16* vrow = vtb + (size_t)(head * HDIM + cch) * NPIX;
        #pragma unroll
        for (int i = 0; i < 4; ++i) {
            const int key0 = i * 128 + s16 * 8;          // mult of 8
            const int pix0 = rowbase + (y0 + (key0 >> 5)) * WW + (key0 & 31);
            union { bf16x8 v; bf16x4 h2[2]; } u;
            u.v = *reinterpret_cast<const bf16x8*>(vrow + pix0);
            const int itl = key0 >> 5;                   // 0..15
            const int hh  = (key0 >> 4) & 1;             // half (keys<16 vs >=16)
            const int g0  = (key0 & 15) >> 2;            // 0 or 2
            #pragma unroll
            for (int h = 0; h < 2; ++h) {
                const int slot = itl * 128 + dtc * 64 + (g0 + h) * 16 + qvc;
                *reinterpret_cast<bf16x4*>(&lds[16384 + (size_t)slot * 8 + hh * 4]) = u.h2[h];
            }
        }
    }

    // ---- Q frags ----
    bf16x8 qf[4];
    #pragma unroll
    for (int qt = 0; qt < 4; ++qt) {
        const int s = qblk64 * 64 + qt * 16 + q16;
        const int pix = ((s >> 10) * HH + rs + ((s >> 5) & 31)) * WW + cs + (s & 31);
        qf[qt] = *reinterpret_cast<const bf16x8*>(qb + (size_t)pix * CC + head * HDIM + g * 8);
    }

    f32x4 acc[2][4];  // [dt][qt]
    f32x4 accl[4];    // lsum accumulators
    #pragma unroll
    for (int b = 0; b < 4; ++b) {
        acc[0][b] = (f32x4){0.f, 0.f, 0.f, 0.f};
        acc[1][b] = (f32x4){0.f, 0.f, 0.f, 0.f};
        accl[b]   = (f32x4){0.f, 0.f, 0.f, 0.f};
    }
    const short one_bf = (short)0x3F80;   // bf16 1.0
    const bf16x8 ones8 = {one_bf, one_bf, one_bf, one_bf,
                          one_bf, one_bf, one_bf, one_bf};

    __syncthreads();

    const bf16x8* kvec = reinterpret_cast<const bf16x8*>(&lds[0]);
    const bf16x8* vvec = reinterpret_cast<const bf16x8*>(&lds[16384]);

    for (int it = 0; it < 16; ++it) {
        const bf16x8 kf0 = kvec[it * 128 + lane];
        const bf16x8 kf1 = kvec[it * 128 + 64 + lane];
        const bf16x8 vf0 = vvec[it * 128 + lane];        // dt=0, permuted 8-key frag
        const bf16x8 vf1 = vvec[it * 128 + 64 + lane];   // dt=1
        #pragma unroll
        for (int qt = 0; qt < 4; ++qt) {
            const f32x4 z = {0.f, 0.f, 0.f, 0.f};
            const f32x4 s0 = __builtin_amdgcn_mfma_f32_16x16x32_bf16(kf0, qf[qt], z, 0, 0, 0);
            const f32x4 s1 = __builtin_amdgcn_mfma_f32_16x16x32_bf16(kf1, qf[qt], z, 0, 0, 0);
            const float p00 = EXP2(s0[0]), p01 = EXP2(s0[1]);
            const float p02 = EXP2(s0[2]), p03 = EXP2(s0[3]);
            const float p10 = EXP2(s1[0]), p11 = EXP2(s1[1]);
            const float p12 = EXP2(s1[2]), p13 = EXP2(s1[3]);
            union { unsigned u[4]; bf16x8 v; } p8;
            p8.u[0] = cvt_pk_bf16(p00, p01); p8.u[1] = cvt_pk_bf16(p02, p03);
            p8.u[2] = cvt_pk_bf16(p10, p11); p8.u[3] = cvt_pk_bf16(p12, p13);
            acc[0][qt] = __builtin_amdgcn_mfma_f32_16x16x32_bf16(vf0, p8.v, acc[0][qt], 0, 0, 0);
            acc[1][qt] = __builtin_amdgcn_mfma_f32_16x16x32_bf16(vf1, p8.v, acc[1][qt], 0, 0, 0);
            accl[qt]   = __builtin_amdgcn_mfma_f32_16x16x32_bf16(ones8, p8.v, accl[qt], 0, 0, 0);
        }
    }

    float* lp = lsb + (size_t)split * LSZ + (size_t)wh * SEQ;
    __hip_bfloat16* Osp = Opm + (size_t)split * OFS + (size_t)win * SEQ * CC + head * HDIM;
    #pragma unroll
    for (int qt = 0; qt < 4; ++qt) {
        const float l = accl[qt][0];
        const int s = qblk64 * 64 + qt * 16 + q16;
        if (g == 0) lp[s] = l;
        #pragma unroll
        for (int dt = 0; dt < 2; ++dt) {
            uint2 st;
            st.x = cvt_pk_bf16(acc[dt][qt][0], acc[dt][qt][1]);
            st.y = cvt_pk_bf16(acc[dt][qt][2], acc[dt][qt][3]);
            *reinterpret_cast<uint2*>(Osp + (size_t)s * CC + dt * 16 + g * 4) = st;
        }
    }
}

// ---------------- Kernel 3: fused split-merge + overlap-add + projection -----
// grid 288; block 256 (4 waves); 16 px/block.
__global__ __launch_bounds__(256) void k_mproj(
    const __hip_bfloat16* __restrict__ Opm, const float* __restrict__ lsb,
    const __hip_bfloat16* __restrict__ wofp, const float* __restrict__ bo,
    float* __restrict__ out)
{
    __shared__ __hip_bfloat16 md[16][264];
    const int tid  = threadIdx.x;
    const int wv_  = tid >> 6;
    const int L    = tid & 63;
    const int head = L >> 3;
    const int p0   = blockIdx.x * 16;

    for (int i = 0; i < 4; ++i) {
        const int pl = wv_ * 4 + i;
        const int p  = p0 + pl;
        const int tt  = p / (HH * WW);
        const int rem = p % (HH * WW);
        const int y   = rem / WW;
        const int xc  = rem % WW;
        f32x4 a = {0.f, 0.f, 0.f, 0.f};
        int cnt = 0;
        for (int wr = 0; wr < 2; ++wr) {
            const int ii = y - wr * 16;
            if (ii < 0 || ii >= 32) continue;
            for (int wc = 0; wc < 2; ++wc) {
                const int jj = xc - wc * 16;
                if (jj < 0 || jj >= 32) continue;
                const int win = wr * 2 + wc;
                const int srow = tt * 1024 + ii * 32 + jj;
                const size_t ob = ((size_t)win * SEQ + srow) * CC + L * 4;
                const size_t li = (size_t)(win * NHEADS + head) * SEQ + srow;
                f32x4 acc4 = {0.f, 0.f, 0.f, 0.f};
                float l = 0.f;
                #pragma unroll
                for (int sp = 0; sp < SPLITS; ++sp) {
                    acc4 += b2f4(*reinterpret_cast<const bf16x4*>(Opm + (size_t)sp * OFS + ob));
                    l += lsb[(size_t)sp * LSZ + li];
                }
                a += acc4 * RCP(l);
                ++cnt;
            }
        }
        const float ic = (cnt == 1) ? 1.0f : ((cnt == 2) ? 0.5f : 0.25f);
        uint2 st;
        st.x = cvt_pk_bf16(a[0] * ic, a[1] * ic);
        st.y = cvt_pk_bf16(a[2] * ic, a[3] * ic);
        *reinterpret_cast<uint2*>(&md[pl][L * 4]) = st;
    }
    __syncthreads();

    const int m16 = L & 15, g = L >> 4;
    bf16x8 xf[8];
    #pragma unroll
    for (int k = 0; k < 8; ++k)
        xf[k] = *reinterpret_cast<const bf16x8*>(&md[m16][k * 32 + g * 8]);

    #pragma unroll
    for (int oct = 0; oct < 4; ++oct) {
        const int octG = wv_ * 4 + oct;
        const int ocb  = octG * 16;
        const __hip_bfloat16* wt = wofp + (size_t)octG * 8 * 512;
        f32x4 c = {0.f, 0.f, 0.f, 0.f};
        #pragma unroll
        for (int k = 0; k < 8; ++k) {
            const bf16x8 wf = *reinterpret_cast<const bf16x8*>(wt + (size_t)k * 512 + L * 8);
            c = __builtin_amdgcn_mfma_f32_16x16x32_bf16(wf, xf[k], c, 0, 0, 0);
        }
        const float4 b4 = *reinterpret_cast<const float4*>(bo + ocb + g * 4);
        c[0] += b4.x; c[1] += b4.y; c[2] += b4.z; c[3] += b4.w;
        *reinterpret_cast<f32x4*>(out + (size_t)(p0 + m16) * CC + ocb + g * 4) = c;
    }
}

extern "C" void kernel_launch(void* const* d_in, const int* in_sizes, int n_in,
                              void* d_out, int out_size, void* d_ws, size_t ws_size,
                              hipStream_t stream)
{
    const float* x   = (const float*)d_in[0];
    const float* lnw = (const float*)d_in[1];
    const float* lnb = (const float*)d_in[2];
    const float* Wq  = (const float*)d_in[3];
    const float* Wk  = (const float*)d_in[4];
    const float* Wv  = (const float*)d_in[5];
    const float* Wo  = (const float*)d_in[6];
    const float* bo  = (const float*)d_in[7];

    __hip_bfloat16* qb   = (__hip_bfloat16*)d_ws;
    __hip_bfloat16* kb   = qb + NPC;
    __hip_bfloat16* vtb  = kb + NPC;
    __hip_bfloat16* xnb  = vtb + NPC;
    __hip_bfloat16* Opm  = xnb + NPC;              // SPLITS*OFS shorts
    __hip_bfloat16* wfp  = Opm + (size_t)SPLITS * OFS;
    __hip_bfloat16* wofp = wfp + 196608;
    float* lsb = (float*)(wofp + 65536);           // SPLITS*LSZ floats

    k_pre<<<1408, 256, 0, stream>>>(Wq, Wk, Wv, Wo, x, lnw, lnb, wfp, wofp, xnb);
    k_qkv<<<432, 256, 0, stream>>>(xnb, wfp, qb, kb, vtb);
    k_attn<<<512, 512, 0, stream>>>(qb, kb, vtb, Opm, lsb);
    k_mproj<<<288, 256, 0, stream>>>(Opm, lsb, wofp, bo, (float*)d_out);
}